// Round 5
// baseline (323.103 us; speedup 1.0000x reference)
//
#include <hip/hip_runtime.h>
#include <stdint.h>

typedef short s16x8 __attribute__((ext_vector_type(8)));
typedef unsigned short u16x8 __attribute__((ext_vector_type(8)));
typedef float f32x4 __attribute__((ext_vector_type(4)));

__device__ __forceinline__ float bf2f(unsigned short u) {
  union { unsigned u; float f; } c; c.u = ((unsigned)u) << 16; return c.f;
}
__device__ __forceinline__ unsigned short f2bf(float f) {
  union { float f; unsigned u; } c; c.f = f;
  unsigned u = c.u + 0x7fffu + ((c.u >> 16) & 1u);
  return (unsigned short)(u >> 16);
}

// async global->LDS, 16B per lane; lds base must be wave-uniform (HW adds lane*16)
__device__ __forceinline__ void g2l16(const void* g, void* l) {
  __builtin_amdgcn_global_load_lds(
      (const __attribute__((address_space(1))) void*)(unsigned long long)g,
      (__attribute__((address_space(3))) void*)(unsigned)(unsigned long long)l,
      16, 0, 0);
}

// C[M,N] = scale*(A[M,K] @ Bt[N,K]^T)(+bias). A,Bt bf16 K-contiguous.
// 512 threads = 8 waves as 2 (row) x 4 (col); wave computes 64x32 via 4x2 MFMA.
// MODE 0: scalar store OutT, bias per-row (bias[M]) if non-null.
// MODE 1: bf16 out, optional per-col bias (bias[N]), LDS-bounce vector store.
// MODE 2: bf16 out = exp(scale*acc), row sums atomically added to rowsum.
// grid.z = batches*nsplit; ks=z%nsplit selects K-chunk, out += ks*sSplit.
template <int MODE, typename OutT>
__global__ __launch_bounds__(512) void gemm_abt(
    const unsigned short* __restrict__ A, int lda,
    const unsigned short* __restrict__ Bt, int ldb,
    OutT* __restrict__ C, int ldc,
    const float* __restrict__ bias,
    float* __restrict__ rowsum,
    int M, int N, int K, int nsplit,
    long long sA, long long sBt, long long sC, long long sSplit,
    float scale)
{
  // As/Bs staging (2x16KB) unioned with the 128x136-padded bounce buffer
  __shared__ __align__(16) unsigned short smem[128 * 136];
  unsigned short* As = smem;
  unsigned short* Bs = smem + 128 * 64;

  const int ks = blockIdx.z % nsplit;
  const int bz = blockIdx.z / nsplit;
  A  += (long long)bz * sA;
  Bt += (long long)bz * sBt;
  C  += (long long)bz * sC + (long long)ks * sSplit;

  const int tile_m = blockIdx.y * 128;
  const int tile_n = blockIdx.x * 128;

  const int tid  = threadIdx.x;
  const int wid  = tid >> 6;        // 0..7
  const int lane = tid & 63;
  const int wm = (wid >> 2) * 64;   // wave's 64-row strip (2 strips)
  const int wn = (wid & 3) * 32;    // wave's 32-col strip (4 strips)
  const int lr = lane & 15;         // fragment row (m for A, n for B)
  const int lq = lane >> 4;         // quad -> k offset lq*8

  const int srow = lane >> 3;       // staging: row within 8-row chunk
  const int skb  = (lane & 7) * 8;  // staging: bf16 offset within 64-wide slab

  f32x4 acc[4][2];
  const f32x4 zero4 = {0.f, 0.f, 0.f, 0.f};
  #pragma unroll
  for (int i = 0; i < 4; ++i)
    #pragma unroll
    for (int j = 0; j < 2; ++j) acc[i][j] = zero4;

  const unsigned short* Arow = A  + (long long)tile_m * lda;
  const unsigned short* Brow = Bt + (long long)tile_n * ldb;

  const int kLen = K / nsplit;
  const int kBeg = ks * kLen;

  for (int k0 = kBeg; k0 < kBeg + kLen; k0 += 64) {
    // stage A[128][64], B[128][64]: 16 chunks each of 8 rows; wave w owns
    // chunks {2w, 2w+1}. LDS layout == row-major tile (no padding).
    #pragma unroll
    for (int c = 0; c < 2; ++c) {
      const int chunk = wid * 2 + c;
      const int row = chunk * 8 + srow;
      g2l16(Arow + (long long)row * lda + k0 + skb, As + chunk * 512);
      g2l16(Brow + (long long)row * ldb + k0 + skb, Bs + chunk * 512);
    }
    __syncthreads();
    #pragma unroll
    for (int kss = 0; kss < 2; ++kss) {
      s16x8 af[4], bfr[2];
      #pragma unroll
      for (int i = 0; i < 4; ++i)
        af[i] = *(const s16x8*)&As[(wm + i * 16 + lr) * 64 + kss * 32 + lq * 8];
      #pragma unroll
      for (int j = 0; j < 2; ++j)
        bfr[j] = *(const s16x8*)&Bs[(wn + j * 16 + lr) * 64 + kss * 32 + lq * 8];
      #pragma unroll
      for (int i = 0; i < 4; ++i)
        #pragma unroll
        for (int j = 0; j < 2; ++j)
          acc[i][j] = __builtin_amdgcn_mfma_f32_16x16x32_bf16(af[i], bfr[j], acc[i][j], 0, 0, 0);
    }
    __syncthreads();
  }

  // epilogue: C/D layout col=lane&15, row=(lane>>4)*4+reg  [m89-verified]
  if constexpr (MODE == 0) {
    #pragma unroll
    for (int i = 0; i < 4; ++i) {
      const int row0 = tile_m + wm + i * 16 + lq * 4;
      #pragma unroll
      for (int j = 0; j < 2; ++j) {
        const int col = tile_n + wn + j * 16 + lr;
        #pragma unroll
        for (int r = 0; r < 4; ++r) {
          float v = acc[i][j][r] * scale;
          if (bias) v += bias[row0 + r];
          C[(long long)(row0 + r) * ldc + col] = (OutT)v;
        }
      }
    }
  } else {
    // bf16 results -> padded LDS tile (ld=136), then vectorized global store
    #pragma unroll
    for (int i = 0; i < 4; ++i) {
      const int lrow0 = wm + i * 16 + lq * 4;
      float rsum[4] = {0.f, 0.f, 0.f, 0.f};
      #pragma unroll
      for (int j = 0; j < 2; ++j) {
        const int lcol = wn + j * 16 + lr;
        float bcol = 0.f;
        if (MODE == 1 && bias) bcol = bias[tile_n + lcol];
        #pragma unroll
        for (int r = 0; r < 4; ++r) {
          float v = acc[i][j][r] * scale + bcol;
          if (MODE == 2) { v = __expf(v); rsum[r] += v; }
          smem[(lrow0 + r) * 136 + lcol] = f2bf(v);
        }
      }
      if (MODE == 2) {
        #pragma unroll
        for (int r = 0; r < 4; ++r) {
          float s = rsum[r];
          s += __shfl_xor(s, 1); s += __shfl_xor(s, 2);
          s += __shfl_xor(s, 4); s += __shfl_xor(s, 8);
          if (lr == 0)
            atomicAdd(&rowsum[(long long)bz * M + tile_m + lrow0 + r], s);
        }
      }
    }
    __syncthreads();
    const int row = tid >> 2;
    const int cb = (tid & 3) * 32;
    unsigned short* Cg = (unsigned short*)C;
    #pragma unroll
    for (int k = 0; k < 4; ++k) {
      u16x8 v = *(const u16x8*)&smem[row * 136 + cb + k * 8];
      *(u16x8*)&Cg[(long long)(tile_m + row) * ldc + tile_n + cb + k * 8] = v;
    }
  }
}

// weights fp32 [C][C] x4 -> bf16 packed; biases bq|bk|bv -> fp32 [1536];
// also zeroes the rowsum accumulator [B*4096]
__global__ __launch_bounds__(256) void cvt_weights(
    const float* __restrict__ wq, const float* __restrict__ wk,
    const float* __restrict__ wv, const float* __restrict__ wo,
    const float* __restrict__ bq, const float* __restrict__ bk,
    const float* __restrict__ bv,
    unsigned short* __restrict__ wb, float* __restrict__ bqkv,
    float* __restrict__ rowsum, int n)
{
  const int i = blockIdx.x * 256 + threadIdx.x;
  if (i < n) {
    wb[i]         = f2bf(wq[i]);
    wb[n + i]     = f2bf(wk[i]);
    wb[2 * n + i] = f2bf(wv[i]);
    wb[3 * n + i] = f2bf(wo[i]);
  }
  if (i < 512) {
    bqkv[i]        = bq[i];
    bqkv[512 + i]  = bk[i];
    bqkv[1024 + i] = bv[i];
  }
  if (i < 8192) rowsum[i] = 0.f;
}

// x fp32 [C][N] -> xT bf16 [N][C], per-batch via grid.z. block (32,8).
__global__ __launch_bounds__(256) void transpose_cn(
    const float* __restrict__ x, unsigned short* __restrict__ xT,
    int C, int N)
{
  __shared__ float tile[32][33];
  const long long boff = (long long)blockIdx.z * C * N;
  const int n0 = blockIdx.x * 32;
  const int c0 = blockIdx.y * 32;
  const int tx = threadIdx.x;
  const int ty = threadIdx.y;
  #pragma unroll
  for (int k = 0; k < 32; k += 8)
    tile[ty + k][tx] = x[boff + (long long)(c0 + ty + k) * N + n0 + tx];
  __syncthreads();
  #pragma unroll
  for (int k = 0; k < 32; k += 8)
    xT[boff + (long long)(n0 + ty + k) * C + c0 + tx] = f2bf(tile[tx][ty + k]);
}

// bf16 transpose: dst[c][r] = src[r][c]
__global__ __launch_bounds__(256) void transpose_bf(
    const unsigned short* __restrict__ src, int srcLd, long long sSrc,
    unsigned short* __restrict__ dst, int dstLd, long long sDst,
    int R, int Cc)
{
  __shared__ unsigned short tile[32][33];
  const int r0 = blockIdx.x * 32;
  const int c0 = blockIdx.y * 32;
  const int tx = threadIdx.x;
  const int ty = threadIdx.y;
  const long long so = (long long)blockIdx.z * sSrc;
  const long long dofs = (long long)blockIdx.z * sDst;
  #pragma unroll
  for (int k = 0; k < 32; k += 8)
    tile[ty + k][tx] = src[so + (long long)(r0 + ty + k) * srcLd + c0 + tx];
  __syncthreads();
  #pragma unroll
  for (int k = 0; k < 32; k += 8)
    dst[dofs + (long long)(c0 + ty + k) * dstLd + r0 + tx] = tile[tx][ty + k];
}

// aO[b][n][c] = (sum of 4 bf16 partial streams) / rowsum[b][n] -> bf16
__global__ __launch_bounds__(256) void reduce4_norm(
    const unsigned short* __restrict__ p, long long L,
    const float* __restrict__ rowsum, unsigned short* __restrict__ o)
{
  const long long i = 8LL * (blockIdx.x * 256 + threadIdx.x);
  const int b = (int)(i >> 21);
  const int n = (int)((i >> 9) & 4095);
  const float inv = 1.0f / rowsum[b * 4096 + n];
  u16x8 a = *(const u16x8*)&p[i];
  u16x8 bb = *(const u16x8*)&p[L + i];
  u16x8 c = *(const u16x8*)&p[2 * L + i];
  u16x8 d = *(const u16x8*)&p[3 * L + i];
  u16x8 w;
  #pragma unroll
  for (int j = 0; j < 8; ++j)
    w[j] = f2bf(((bf2f(a[j]) + bf2f(bb[j])) + (bf2f(c[j]) + bf2f(d[j]))) * inv);
  *(u16x8*)&o[i] = w;
}

extern "C" void kernel_launch(void* const* d_in, const int* in_sizes, int n_in,
                              void* d_out, int out_size, void* d_ws, size_t ws_size,
                              hipStream_t stream) {
  (void)in_sizes; (void)n_in; (void)out_size; (void)ws_size;
  const float* x  = (const float*)d_in[0];
  const float* wq = (const float*)d_in[1];
  const float* bq = (const float*)d_in[2];
  const float* wk = (const float*)d_in[3];
  const float* bk = (const float*)d_in[4];
  const float* wv = (const float*)d_in[5];
  const float* bv = (const float*)d_in[6];
  const float* wo = (const float*)d_in[7];
  const float* bo = (const float*)d_in[8];
  float* out = (float*)d_out;

  const int Cc = 512, N = 4096, Bn = 2, C3 = 1536;
  const int CC = Cc * Cc;                    // 262,144
  const long long NC  = (long long)N * Cc;   // 2,097,152
  const long long NC3 = (long long)N * C3;   // 6,291,456
  const long long NN  = (long long)N * N;    // 16,777,216

  char* wsb = (char*)d_ws;
  unsigned short* wb   = (unsigned short*)wsb;                          // 4*CC bf16
  float*          bqkv = (float*)(wsb + 4LL * CC * 2);                  // 1536 fp32
  unsigned short* xT   = (unsigned short*)(wsb + 4LL * CC * 2 + 8192);  // [B][N][C]
  unsigned short* qkvT = xT + Bn * NC;                                  // [B][N][1536]
  unsigned short* vv   = qkvT + Bn * NC3;                               // [B][C][N]
  unsigned short* aO   = vv + Bn * NC;                                  // [B][N][C]
  unsigned short* S    = aO + Bn * NC;                                  // [B][N][N] P_unnorm
  unsigned short* part = S + Bn * NN;                                   // [4][B][N][C] bf16
  float*          rsum = (float*)(part + 4LL * Bn * NC);                // [B][4096]

  unsigned short* wob = wb + 3LL * CC;
  const float inv_sqrt_c = 0.044194173824159216f;  // 1/sqrt(512)

  cvt_weights<<<dim3((CC + 255) / 256), 256, 0, stream>>>(
      wq, wk, wv, wo, bq, bk, bv, wb, bqkv, rsum, CC);
  transpose_cn<<<dim3(N / 32, Cc / 32, Bn), dim3(32, 8), 0, stream>>>(x, xT, Cc, N);

  // qkvT[n,d] = sum_c xT[n,c] Wqkv[d,c] + bqkv[d]   (d 0..1535; q|k|v)
  gemm_abt<1, unsigned short><<<dim3(C3 / 128, N / 128, Bn), 512, 0, stream>>>(
      xT, Cc, wb, Cc, qkvT, C3, bqkv, nullptr, N, C3, Cc, 1,
      NC, 0, NC3, 0, 1.0f);
  // vv[c,n] = qkvT[n, 1024+c]
  transpose_bf<<<dim3(N / 32, Cc / 32, Bn), dim3(32, 8), 0, stream>>>(
      qkvT + 1024, C3, NC3, vv, N, NC, N, Cc);
  // P_unnorm[n,m] = exp( (1/sqrt(C)) sum_c q[n,c] k[m,c] ); rsum += row sums
  gemm_abt<2, unsigned short><<<dim3(N / 128, N / 128, Bn), 512, 0, stream>>>(
      qkvT, C3, qkvT + 512, C3, S, N, nullptr, rsum, N, N, Cc, 1,
      NC3, NC3, NN, 0, inv_sqrt_c);
  // part[ks][b][n][c] = sum_{m in split ks} P_unnorm[n,m] vv[c,m]  (bf16 partials)
  gemm_abt<1, unsigned short><<<dim3(Cc / 128, N / 128, Bn * 4), 512, 0, stream>>>(
      S, N, vv, N, part, Cc, nullptr, nullptr, N, Cc, N, 4,
      NN, NC, NC, (long long)Bn * NC, 1.0f);
  // aO = (sum of partials) / rowsum   -> normalized attention output
  reduce4_norm<<<dim3((int)((Bn * NC) / 2048)), 256, 0, stream>>>(
      part, (long long)Bn * NC, rsum, aO);
  // out[d,n] = sum_c wo[d,c] aO[n,c] + bo[d]   (fp32, lands in [B][C][H][W])
  gemm_abt<0, float><<<dim3(N / 128, Cc / 128, Bn), 512, 0, stream>>>(
      wob, Cc, aO, Cc, out, N, bo, nullptr, Cc, N, Cc, 1,
      0, NC, NC, 0, 1.0f);
}

// Round 6
// 282.868 us; speedup vs baseline: 1.1422x; 1.1422x over previous
//
#include <hip/hip_runtime.h>
#include <stdint.h>

typedef short s16x8 __attribute__((ext_vector_type(8)));
typedef unsigned short u16x8 __attribute__((ext_vector_type(8)));
typedef float f32x4 __attribute__((ext_vector_type(4)));

__device__ __forceinline__ float bf2f(unsigned short u) {
  union { unsigned u; float f; } c; c.u = ((unsigned)u) << 16; return c.f;
}
__device__ __forceinline__ unsigned short f2bf(float f) {
  union { float f; unsigned u; } c; c.f = f;
  unsigned u = c.u + 0x7fffu + ((c.u >> 16) & 1u);
  return (unsigned short)(u >> 16);
}

// async global->LDS, 16B per lane; lds base must be wave-uniform (HW adds lane*16)
__device__ __forceinline__ void g2l16(const void* g, void* l) {
  __builtin_amdgcn_global_load_lds(
      (const __attribute__((address_space(1))) void*)(unsigned long long)g,
      (__attribute__((address_space(3))) void*)(unsigned)(unsigned long long)l,
      16, 0, 0);
}

// C[M,N] = scale*(A[M,K] @ Bt[N,K]^T)(+bias). A,Bt bf16 K-contiguous.
// 256 thr = 4 waves, each 64x64 (4x4 MFMA tiles) -- m97 shape.
// LDS staging XOR-swizzled: chunk c (16B) of row r lives at slot c^(r&7),
// making MFMA fragment reads 2-way instead of 16-way bank-conflicted.
// MODE 0: scalar store OutT, bias per-row (bias[M]) if non-null.
// MODE 1: bf16 out, optional per-col bias (bias[N]), LDS-bounce vector store.
// MODE 2: bf16 out = exp(scale*acc), row sums atomically added to rowsum.
// grid.z = batches*nsplit; ks=z%nsplit selects K-chunk, out += ks*sSplit.
template <int MODE, typename OutT>
__global__ __launch_bounds__(256) void gemm_abt(
    const unsigned short* __restrict__ A, int lda,
    const unsigned short* __restrict__ Bt, int ldb,
    OutT* __restrict__ C, int ldc,
    const float* __restrict__ bias,
    float* __restrict__ rowsum,
    int M, int N, int K, int nsplit,
    long long sA, long long sBt, long long sC, long long sSplit,
    float scale)
{
  // As/Bs staging (2x16KB) unioned with the 128x136-padded bounce buffer
  __shared__ __align__(16) unsigned short smem[128 * 136];
  unsigned short* As = smem;
  unsigned short* Bs = smem + 128 * 64;

  const int ks = blockIdx.z % nsplit;
  const int bz = blockIdx.z / nsplit;
  A  += (long long)bz * sA;
  Bt += (long long)bz * sBt;
  C  += (long long)bz * sC + (long long)ks * sSplit;

  const int tile_m = blockIdx.y * 128;
  const int tile_n = blockIdx.x * 128;

  const int tid  = threadIdx.x;
  const int wid  = tid >> 6;
  const int lane = tid & 63;
  const int wm = (wid >> 1) * 64;   // wave's 64-row strip
  const int wn = (wid & 1) * 64;    // wave's 64-col strip
  const int lr = lane & 15;         // fragment row (m for A, n for B)
  const int lq = lane >> 4;         // quad -> k offset lq*8

  const int srow = lane >> 3;                         // row within 8-row chunk
  const int scol = ((lane & 7) ^ (srow & 7)) * 8;     // XOR-swizzled col chunk

  f32x4 acc[4][4];
  const f32x4 zero4 = {0.f, 0.f, 0.f, 0.f};
  #pragma unroll
  for (int i = 0; i < 4; ++i)
    #pragma unroll
    for (int j = 0; j < 4; ++j) acc[i][j] = zero4;

  const unsigned short* Arow = A  + (long long)tile_m * lda;
  const unsigned short* Brow = Bt + (long long)tile_n * ldb;

  const int kLen = K / nsplit;
  const int kBeg = ks * kLen;

  for (int k0 = kBeg; k0 < kBeg + kLen; k0 += 64) {
    // stage A[128][64], B[128][64]: 16 chunks of 1KB; wave w owns 4w..4w+3.
    // lane (srow,slot) fetches global col-chunk slot^(r&7) -> LDS slot `slot`.
    #pragma unroll
    for (int c = 0; c < 4; ++c) {
      const int chunk = wid * 4 + c;
      const int row = chunk * 8 + srow;
      g2l16(Arow + (long long)row * lda + k0 + scol, As + chunk * 512);
      g2l16(Brow + (long long)row * ldb + k0 + scol, Bs + chunk * 512);
    }
    __syncthreads();
    #pragma unroll
    for (int kss = 0; kss < 2; ++kss) {
      const int cch = kss * 4 + lq;                 // 16B-chunk index in row
      s16x8 af[4], bfr[4];
      #pragma unroll
      for (int i = 0; i < 4; ++i) {
        const int row = wm + i * 16 + lr;
        af[i] = *(const s16x8*)&As[row * 64 + ((cch ^ (row & 7)) * 8)];
      }
      #pragma unroll
      for (int j = 0; j < 4; ++j) {
        const int row = wn + j * 16 + lr;
        bfr[j] = *(const s16x8*)&Bs[row * 64 + ((cch ^ (row & 7)) * 8)];
      }
      #pragma unroll
      for (int i = 0; i < 4; ++i)
        #pragma unroll
        for (int j = 0; j < 4; ++j)
          acc[i][j] = __builtin_amdgcn_mfma_f32_16x16x32_bf16(af[i], bfr[j], acc[i][j], 0, 0, 0);
    }
    __syncthreads();
  }

  // epilogue: C/D layout col=lane&15, row=(lane>>4)*4+reg  [m89-verified]
  if constexpr (MODE == 0) {
    #pragma unroll
    for (int i = 0; i < 4; ++i) {
      const int row0 = tile_m + wm + i * 16 + lq * 4;
      #pragma unroll
      for (int j = 0; j < 4; ++j) {
        const int col = tile_n + wn + j * 16 + lr;
        #pragma unroll
        for (int r = 0; r < 4; ++r) {
          float v = acc[i][j][r] * scale;
          if (bias) v += bias[row0 + r];
          C[(long long)(row0 + r) * ldc + col] = (OutT)v;
        }
      }
    }
  } else {
    // bf16 results -> padded LDS tile (ld=136), then vectorized global store
    #pragma unroll
    for (int i = 0; i < 4; ++i) {
      const int lrow0 = wm + i * 16 + lq * 4;
      float rsum[4] = {0.f, 0.f, 0.f, 0.f};
      #pragma unroll
      for (int j = 0; j < 4; ++j) {
        const int lcol = wn + j * 16 + lr;
        float bcol = 0.f;
        if (MODE == 1 && bias) bcol = bias[tile_n + lcol];
        #pragma unroll
        for (int r = 0; r < 4; ++r) {
          float v = acc[i][j][r] * scale + bcol;
          if (MODE == 2) { v = __expf(v); rsum[r] += v; }
          smem[(lrow0 + r) * 136 + lcol] = f2bf(v);
        }
      }
      if (MODE == 2) {
        #pragma unroll
        for (int r = 0; r < 4; ++r) {
          float s = rsum[r];
          s += __shfl_xor(s, 1); s += __shfl_xor(s, 2);
          s += __shfl_xor(s, 4); s += __shfl_xor(s, 8);
          if (lr == 0)
            atomicAdd(&rowsum[(long long)bz * M + tile_m + lrow0 + r], s);
        }
      }
    }
    __syncthreads();
    const int row = tid >> 1;
    const int cb = (tid & 1) * 64;
    unsigned short* Cg = (unsigned short*)C;
    #pragma unroll
    for (int k = 0; k < 8; ++k) {
      u16x8 v = *(const u16x8*)&smem[row * 136 + cb + k * 8];
      *(u16x8*)&Cg[(long long)(tile_m + row) * ldc + tile_n + cb + k * 8] = v;
    }
  }
}

// weights fp32 [C][C] x4 -> bf16 packed; biases bq|bk|bv -> fp32 [1536];
// also zeroes the rowsum accumulator [B*4096]
__global__ __launch_bounds__(256) void cvt_weights(
    const float* __restrict__ wq, const float* __restrict__ wk,
    const float* __restrict__ wv, const float* __restrict__ wo,
    const float* __restrict__ bq, const float* __restrict__ bk,
    const float* __restrict__ bv,
    unsigned short* __restrict__ wb, float* __restrict__ bqkv,
    float* __restrict__ rowsum, int n)
{
  const int i = blockIdx.x * 256 + threadIdx.x;
  if (i < n) {
    wb[i]         = f2bf(wq[i]);
    wb[n + i]     = f2bf(wk[i]);
    wb[2 * n + i] = f2bf(wv[i]);
    wb[3 * n + i] = f2bf(wo[i]);
  }
  if (i < 512) {
    bqkv[i]        = bq[i];
    bqkv[512 + i]  = bk[i];
    bqkv[1024 + i] = bv[i];
  }
  if (i < 8192) rowsum[i] = 0.f;
}

// x fp32 [C][N] -> xT bf16 [N][C], per-batch via grid.z. block (32,8).
__global__ __launch_bounds__(256) void transpose_cn(
    const float* __restrict__ x, unsigned short* __restrict__ xT,
    int C, int N)
{
  __shared__ float tile[32][33];
  const long long boff = (long long)blockIdx.z * C * N;
  const int n0 = blockIdx.x * 32;
  const int c0 = blockIdx.y * 32;
  const int tx = threadIdx.x;
  const int ty = threadIdx.y;
  #pragma unroll
  for (int k = 0; k < 32; k += 8)
    tile[ty + k][tx] = x[boff + (long long)(c0 + ty + k) * N + n0 + tx];
  __syncthreads();
  #pragma unroll
  for (int k = 0; k < 32; k += 8)
    xT[boff + (long long)(n0 + ty + k) * C + c0 + tx] = f2bf(tile[tx][ty + k]);
}

// bf16 transpose: dst[c][r] = src[r][c]
__global__ __launch_bounds__(256) void transpose_bf(
    const unsigned short* __restrict__ src, int srcLd, long long sSrc,
    unsigned short* __restrict__ dst, int dstLd, long long sDst,
    int R, int Cc)
{
  __shared__ unsigned short tile[32][33];
  const int r0 = blockIdx.x * 32;
  const int c0 = blockIdx.y * 32;
  const int tx = threadIdx.x;
  const int ty = threadIdx.y;
  const long long so = (long long)blockIdx.z * sSrc;
  const long long dofs = (long long)blockIdx.z * sDst;
  #pragma unroll
  for (int k = 0; k < 32; k += 8)
    tile[ty + k][tx] = src[so + (long long)(r0 + ty + k) * srcLd + c0 + tx];
  __syncthreads();
  #pragma unroll
  for (int k = 0; k < 32; k += 8)
    dst[dofs + (long long)(c0 + ty + k) * dstLd + r0 + tx] = tile[tx][ty + k];
}

// aO[b][n][c] = (sum of 4 bf16 partial streams) / rowsum[b][n] -> bf16
__global__ __launch_bounds__(256) void reduce4_norm(
    const unsigned short* __restrict__ p, long long L,
    const float* __restrict__ rowsum, unsigned short* __restrict__ o)
{
  const long long i = 8LL * (blockIdx.x * 256 + threadIdx.x);
  const int b = (int)(i >> 21);
  const int n = (int)((i >> 9) & 4095);
  const float inv = 1.0f / rowsum[b * 4096 + n];
  u16x8 a = *(const u16x8*)&p[i];
  u16x8 bb = *(const u16x8*)&p[L + i];
  u16x8 c = *(const u16x8*)&p[2 * L + i];
  u16x8 d = *(const u16x8*)&p[3 * L + i];
  u16x8 w;
  #pragma unroll
  for (int j = 0; j < 8; ++j)
    w[j] = f2bf(((bf2f(a[j]) + bf2f(bb[j])) + (bf2f(c[j]) + bf2f(d[j]))) * inv);
  *(u16x8*)&o[i] = w;
}

extern "C" void kernel_launch(void* const* d_in, const int* in_sizes, int n_in,
                              void* d_out, int out_size, void* d_ws, size_t ws_size,
                              hipStream_t stream) {
  (void)in_sizes; (void)n_in; (void)out_size; (void)ws_size;
  const float* x  = (const float*)d_in[0];
  const float* wq = (const float*)d_in[1];
  const float* bq = (const float*)d_in[2];
  const float* wk = (const float*)d_in[3];
  const float* bk = (const float*)d_in[4];
  const float* wv = (const float*)d_in[5];
  const float* bv = (const float*)d_in[6];
  const float* wo = (const float*)d_in[7];
  const float* bo = (const float*)d_in[8];
  float* out = (float*)d_out;

  const int Cc = 512, N = 4096, Bn = 2, C3 = 1536;
  const int CC = Cc * Cc;                    // 262,144
  const long long NC  = (long long)N * Cc;   // 2,097,152
  const long long NC3 = (long long)N * C3;   // 6,291,456
  const long long NN  = (long long)N * N;    // 16,777,216

  char* wsb = (char*)d_ws;
  unsigned short* wb   = (unsigned short*)wsb;                          // 4*CC bf16
  float*          bqkv = (float*)(wsb + 4LL * CC * 2);                  // 1536 fp32
  unsigned short* xT   = (unsigned short*)(wsb + 4LL * CC * 2 + 8192);  // [B][N][C]
  unsigned short* qkvT = xT + Bn * NC;                                  // [B][N][1536]
  unsigned short* vv   = qkvT + Bn * NC3;                               // [B][C][N]
  unsigned short* aO   = vv + Bn * NC;                                  // [B][N][C]
  unsigned short* S    = aO + Bn * NC;                                  // [B][N][N] P_unnorm
  unsigned short* part = S + Bn * NN;                                   // [4][B][N][C] bf16
  float*          rsum = (float*)(part + 4LL * Bn * NC);                // [B][4096]

  unsigned short* wob = wb + 3LL * CC;
  const float inv_sqrt_c = 0.044194173824159216f;  // 1/sqrt(512)

  cvt_weights<<<dim3((CC + 255) / 256), 256, 0, stream>>>(
      wq, wk, wv, wo, bq, bk, bv, wb, bqkv, rsum, CC);
  transpose_cn<<<dim3(N / 32, Cc / 32, Bn), dim3(32, 8), 0, stream>>>(x, xT, Cc, N);

  // qkvT[n,d] = sum_c xT[n,c] Wqkv[d,c] + bqkv[d]   (d 0..1535; q|k|v)
  gemm_abt<1, unsigned short><<<dim3(C3 / 128, N / 128, Bn), 256, 0, stream>>>(
      xT, Cc, wb, Cc, qkvT, C3, bqkv, nullptr, N, C3, Cc, 1,
      NC, 0, NC3, 0, 1.0f);
  // vv[c,n] = qkvT[n, 1024+c]
  transpose_bf<<<dim3(N / 32, Cc / 32, Bn), dim3(32, 8), 0, stream>>>(
      qkvT + 1024, C3, NC3, vv, N, NC, N, Cc);
  // P_unnorm[n,m] = exp( (1/sqrt(C)) sum_c q[n,c] k[m,c] ); rsum += row sums
  gemm_abt<2, unsigned short><<<dim3(N / 128, N / 128, Bn), 256, 0, stream>>>(
      qkvT, C3, qkvT + 512, C3, S, N, nullptr, rsum, N, N, Cc, 1,
      NC3, NC3, NN, 0, inv_sqrt_c);
  // part[ks][b][n][c] = sum_{m in split ks} P_unnorm[n,m] vv[c,m]  (bf16 partials)
  gemm_abt<1, unsigned short><<<dim3(Cc / 128, N / 128, Bn * 4), 256, 0, stream>>>(
      S, N, vv, N, part, Cc, nullptr, nullptr, N, Cc, N, 4,
      NN, NC, NC, (long long)Bn * NC, 1.0f);
  // aO = (sum of partials) / rowsum   -> normalized attention output
  reduce4_norm<<<dim3((int)((Bn * NC) / 2048)), 256, 0, stream>>>(
      part, (long long)Bn * NC, rsum, aO);
  // out[d,n] = sum_c wo[d,c] aO[n,c] + bo[d]   (fp32, lands in [B][C][H][W])
  gemm_abt<0, float><<<dim3(N / 128, Cc / 128, Bn), 256, 0, stream>>>(
      wob, Cc, aO, Cc, out, N, bo, nullptr, Cc, N, Cc, 1,
      0, NC, NC, 0, 1.0f);
}